// Round 12
// baseline (89.479 us; speedup 1.0000x reference)
//
#include <hip/hip_runtime.h>
#include <hip/hip_bf16.h>

#define NROWS 8192
#define NDIM  256
#define KNN   8
#define TCOL  32                          // j-cols per tile
#define BLK_ROWS 128                      // 4 waves x 32 rows (R=1)

typedef __attribute__((ext_vector_type(8)))  short bf16x8;
typedef __attribute__((ext_vector_type(16))) float f32x16;

// ---- workspace layout (bytes) ----
// ebT chunk-major: ushort ebT[32][NROWS][8] — chunk c holds dims 8c..8c+7 of
// every row. Any 32-consecutive-row fragment load = contiguous 512 B.
#define WS_EBT 0                          // 4 MiB
#define WS_SQN (4*1024*1024)              // 32 KiB
#define WS_PCS (WS_SQN + 32*1024)         // 128 x 256 f32 = 128 KiB
#define WS_ACC (WS_PCS + 128*1024)        // gacc[0..2] + counter
#define WS_KNN (WS_ACC + 1024)            // [16][NROWS][KNN] f32 = 4 MiB

// e -> bf16 chunk-major, per-row squared norms, per-block colsum partials.
__global__ void k_prep(const float* __restrict__ e,
                       ushort* __restrict__ ebt,
                       float* __restrict__ sqn,
                       float* __restrict__ pcs,
                       float* __restrict__ gacc) {
  __shared__ float lcs[NDIM];
  const int tid  = threadIdx.x;
  const int lane = tid & 63;
  const int wv   = tid >> 6;
  if (blockIdx.x == 0 && tid < 8) ((int*)gacc)[tid] = 0;
  lcs[tid] = 0.f;
  __syncthreads();
  const int chunk = lane >> 1;
  const int half  = lane & 1;
  float4 cs = {0.f, 0.f, 0.f, 0.f};
  #pragma unroll
  for (int r = 0; r < 16; ++r) {
    const int row = blockIdx.x * 64 + wv * 16 + r;
    const float4 v = *reinterpret_cast<const float4*>(e + (size_t)row * NDIM + lane * 4);
    ushort4 o;
    __hip_bfloat16 b0 = __float2bfloat16(v.x), b1 = __float2bfloat16(v.y);
    __hip_bfloat16 b2 = __float2bfloat16(v.z), b3 = __float2bfloat16(v.w);
    o.x = *reinterpret_cast<ushort*>(&b0); o.y = *reinterpret_cast<ushort*>(&b1);
    o.z = *reinterpret_cast<ushort*>(&b2); o.w = *reinterpret_cast<ushort*>(&b3);
    *reinterpret_cast<ushort4*>(ebt + ((size_t)(chunk * NROWS + row) * 8 + half * 4)) = o;
    float acc = v.x*v.x + v.y*v.y + v.z*v.z + v.w*v.w;
    #pragma unroll
    for (int off = 32; off > 0; off >>= 1) acc += __shfl_down(acc, off);
    if (lane == 0) sqn[row] = acc;
    cs.x += v.x; cs.y += v.y; cs.z += v.z; cs.w += v.w;
  }
  atomicAdd(&lcs[lane * 4 + 0], cs.x);
  atomicAdd(&lcs[lane * 4 + 1], cs.y);
  atomicAdd(&lcs[lane * 4 + 2], cs.z);
  atomicAdd(&lcs[lane * 4 + 3], cs.w);
  __syncthreads();
  pcs[blockIdx.x * NDIM + tid] = lcs[tid];
}

// ---- selection helpers (MAX-key; key = dot - nj/2, larger = nearer) ----
__device__ __forceinline__ void CEmax(float& x, float& y) {
  const float hi = fmaxf(x, y);
  y = fminf(x, y);
  x = hi;
}
__device__ __forceinline__ void clean8max(float* s) {   // bitonic -> descending
  CEmax(s[0],s[4]); CEmax(s[1],s[5]); CEmax(s[2],s[6]); CEmax(s[3],s[7]);
  CEmax(s[0],s[2]); CEmax(s[1],s[3]); CEmax(s[4],s[6]); CEmax(s[5],s[7]);
  CEmax(s[0],s[1]); CEmax(s[2],s[3]); CEmax(s[4],s[5]); CEmax(s[6],s[7]);
}
__device__ __forceinline__ void ins8max(float* m, const float c) {  // desc insert
  m[7] = __builtin_amdgcn_fmed3f(m[6], m[7], c);
  m[6] = __builtin_amdgcn_fmed3f(m[5], m[6], c);
  m[5] = __builtin_amdgcn_fmed3f(m[4], m[5], c);
  m[4] = __builtin_amdgcn_fmed3f(m[3], m[4], c);
  m[3] = __builtin_amdgcn_fmed3f(m[2], m[3], c);
  m[2] = __builtin_amdgcn_fmed3f(m[1], m[2], c);
  m[1] = __builtin_amdgcn_fmed3f(m[0], m[1], c);
  m[0] = fmaxf(m[0], c);
}
__device__ __forceinline__ void CEmin(float& x, float& y) {
  const float lo = fminf(x, y);
  y = fmaxf(x, y);
  x = lo;
}
__device__ __forceinline__ void clean8min(float* s) {   // bitonic -> ascending
  CEmin(s[0],s[4]); CEmin(s[1],s[5]); CEmin(s[2],s[6]); CEmin(s[3],s[7]);
  CEmin(s[0],s[2]); CEmin(s[1],s[3]); CEmin(s[4],s[6]); CEmin(s[5],s[7]);
  CEmin(s[0],s[1]); CEmin(s[2],s[3]); CEmin(s[4],s[5]); CEmin(s[6],s[7]);
}

// Fused Gram + top-8. R=1, 4 blocks/CU. Hybrid jf sourcing to balance pipes:
//   kk 0..7  (chunks  0..15): LDS (8 KB/tile staged via global_load_lds)
//   kk 8..15 (chunks 16..31): direct global loads (coalesced 512 B segs,
//            L1-shared across the block's 4 waves; ebt is L2-resident)
// 4 x 8 KB LDS buffers, 2 tiles staged per period -> ONE barrier per 2 iters.
// Global loads use uniform SGPR bases + one shared voffset; rolling window
// of 4 live jg fragments keeps regs ~115 (r11's spill lesson).
__launch_bounds__(256, 4)
__global__ void k_main(const ushort* __restrict__ ebt,
                       const float* __restrict__ sqn,
                       float* __restrict__ knn_out,
                       int jrange, int jsplit) {
  __shared__ ushort lbuf[4][4096];          // 4 x 8 KiB
  char* const lraw = reinterpret_cast<char*>(&lbuf[0][0]);

  const int tid  = threadIdx.x;
  const int lane = tid & 63;
  const int wv   = tid >> 6;
  const int col  = lane & 31;
  const int hi   = lane >> 5;
  const int rowi = blockIdx.x * BLK_ROWS + wv * 32 + col;
  const int split = blockIdx.y;
  const int jbase = split * jrange;

  // i-fragments (all 32 chunks): coalesced 512 B per half-wave.
  bf16x8 ifr[16];
  #pragma unroll
  for (int kk = 0; kk < 16; ++kk)
    ifr[kk] = *reinterpret_cast<const bf16x8*>(
        ebt + (size_t)((2 * kk + hi) * NROWS + rowi) * 8);
  const float ni = sqn[rowi];

  float m[KNN];
  #pragma unroll
  for (int i = 0; i < KNN; ++i) m[i] = -1e30f;

  // stage source pointers (chunks 0..15 only): sp[s] covers c = s*8+(tid>>5)
  const ushort* sp[2];
  #pragma unroll
  for (int s = 0; s < 2; ++s) {
    const int c = s * 8 + (tid >> 5);
    sp[s] = ebt + (size_t)(c * NROWS + jbase + (tid & 31)) * 8;
  }
  const int lbase = hi * 512 + col * 16;    // LDS lane base (contiguous)

  // shared voffset for global jf (chunks 16..31): uniform base per kk.
  int voff = (hi * NROWS + jbase + col) * 8;

  auto STAGE = [&](int bufc) {              // stage ONE tile (8 KB), advance
    #pragma unroll
    for (int s = 0; s < 2; ++s) {
      __builtin_amdgcn_global_load_lds(
          (const __attribute__((address_space(1))) void*)sp[s],
          (__attribute__((address_space(3))) void*)(
              lraw + bufc * 8192 + s * 4096 + wv * 1024),
          16, 0, 0);
      sp[s] += TCOL * 8;
    }
  };

  const float* njp = sqn + jbase;
  const int nT = jrange / TCOL;             // 16

  STAGE(0); STAGE(1);
  asm volatile("s_waitcnt vmcnt(0)" ::: "memory");
  __syncthreads();

  auto G = [&](int kk) -> bf16x8 {          // kk in 8..15, chunk 2kk+hi
    return *reinterpret_cast<const bf16x8*>(
        ebt + (size_t)(2 * kk) * NROWS * 8 + voff);
  };
  auto L = [&](int bufc, int kk) -> bf16x8 {  // kk in 0..7
    return *reinterpret_cast<const bf16x8*>(
        lraw + bufc * 8192 + kk * 1024 + lbase);
  };

  auto BODY = [&](int bufc) {
    f32x16 acc;
    #pragma unroll
    for (int g = 0; g < 4; ++g) {
      const float4 nj4 = *reinterpret_cast<const float4*>(njp + g * 8 + hi * 4);
      acc[g*4+0] = -0.5f * nj4.x; acc[g*4+1] = -0.5f * nj4.y;
      acc[g*4+2] = -0.5f * nj4.z; acc[g*4+3] = -0.5f * nj4.w;
    }
    // rolling-window interleave: <=4 jg fragments live at once
    bf16x8 a0 = G(8),  a1 = G(9);
    acc = __builtin_amdgcn_mfma_f32_32x32x16_bf16(L(bufc,0), ifr[0], acc, 0,0,0);
    acc = __builtin_amdgcn_mfma_f32_32x32x16_bf16(L(bufc,1), ifr[1], acc, 0,0,0);
    bf16x8 a2 = G(10), a3 = G(11);
    acc = __builtin_amdgcn_mfma_f32_32x32x16_bf16(L(bufc,2), ifr[2], acc, 0,0,0);
    acc = __builtin_amdgcn_mfma_f32_32x32x16_bf16(L(bufc,3), ifr[3], acc, 0,0,0);
    acc = __builtin_amdgcn_mfma_f32_32x32x16_bf16(a0, ifr[8], acc, 0,0,0);
    acc = __builtin_amdgcn_mfma_f32_32x32x16_bf16(a1, ifr[9], acc, 0,0,0);
    bf16x8 a4 = G(12), a5 = G(13);
    acc = __builtin_amdgcn_mfma_f32_32x32x16_bf16(L(bufc,4), ifr[4], acc, 0,0,0);
    acc = __builtin_amdgcn_mfma_f32_32x32x16_bf16(L(bufc,5), ifr[5], acc, 0,0,0);
    acc = __builtin_amdgcn_mfma_f32_32x32x16_bf16(a2, ifr[10], acc, 0,0,0);
    acc = __builtin_amdgcn_mfma_f32_32x32x16_bf16(a3, ifr[11], acc, 0,0,0);
    bf16x8 a6 = G(14), a7 = G(15);
    acc = __builtin_amdgcn_mfma_f32_32x32x16_bf16(L(bufc,6), ifr[6], acc, 0,0,0);
    acc = __builtin_amdgcn_mfma_f32_32x32x16_bf16(L(bufc,7), ifr[7], acc, 0,0,0);
    acc = __builtin_amdgcn_mfma_f32_32x32x16_bf16(a4, ifr[12], acc, 0,0,0);
    acc = __builtin_amdgcn_mfma_f32_32x32x16_bf16(a5, ifr[13], acc, 0,0,0);
    acc = __builtin_amdgcn_mfma_f32_32x32x16_bf16(a6, ifr[14], acc, 0,0,0);
    acc = __builtin_amdgcn_mfma_f32_32x32x16_bf16(a7, ifr[15], acc, 0,0,0);

    #pragma unroll
    for (int q = 0; q < 16; ++q) ins8max(m, acc[q]);

    njp += TCOL;
    voff += TCOL * 8;
  };

  for (int t = 0; t < nT; t += 2) {
    if (t + 2 < nT) { STAGE((t + 2) & 3); STAGE((t + 3) & 3); }
    BODY(t & 3);
    BODY((t + 1) & 3);
    asm volatile("s_waitcnt vmcnt(0)" ::: "memory");
    __syncthreads();
  }

  // merge k-half lists (lane <-> lane+32): top-8 of two descending lists is
  // elementwise max(a_k, b_{7-k}) (bitonic) -> clean. dist = ni - 2*key.
  float g[KNN];
  #pragma unroll
  for (int k = 0; k < KNN; ++k)
    g[k] = fmaxf(m[k], __shfl_xor(m[KNN - 1 - k], 32));
  clean8max(g);
  if (hi == 0) {
    float* dst = knn_out + ((size_t)split * NROWS + rowi) * KNN;
    #pragma unroll
    for (int k = 0; k < KNN; ++k)
      dst[k] = fmaxf(fmaf(-2.0f, g[k], ni), 0.0f);   // ascending distances
  }
}

// Merge jsplit ascending sorted 8-lists per row; reduce sum8/S2; block 0
// reduces colsum partials -> Q; last finishing block computes the scalar.
__global__ void k_final(const float* __restrict__ knn,
                        const float* __restrict__ sqn,
                        const float* __restrict__ pcs,
                        float* __restrict__ gacc,
                        float* __restrict__ out, int jsplit) {
  const int tid = threadIdx.x;
  const int row = blockIdx.x * blockDim.x + tid;
  float m[KNN];
  const float* p0 = knn + (size_t)row * KNN;
  #pragma unroll
  for (int i = 0; i < KNN; ++i) m[i] = p0[i];
  for (int s = 1; s < jsplit; ++s) {
    const float* p = knn + ((size_t)s * NROWS + row) * KNN;
    float b[KNN];
    #pragma unroll
    for (int i = 0; i < KNN; ++i) b[i] = p[i];
    #pragma unroll
    for (int k = 0; k < KNN; ++k) m[k] = fminf(m[k], b[KNN - 1 - k]);
    clean8min(m);
  }
  float rs = 0.f;
  #pragma unroll
  for (int i = 0; i < KNN; ++i) rs += m[i];
  float s2 = sqn[row];

  __shared__ float red[2][4];
  #pragma unroll
  for (int off = 32; off > 0; off >>= 1) {
    rs += __shfl_down(rs, off);
    s2 += __shfl_down(s2, off);
  }
  if ((tid & 63) == 0) { red[0][tid >> 6] = rs; red[1][tid >> 6] = s2; }
  __syncthreads();
  if (tid == 0) {
    atomicAdd(&gacc[0], red[0][0] + red[0][1] + red[0][2] + red[0][3]);
    atomicAdd(&gacc[1], red[1][0] + red[1][1] + red[1][2] + red[1][3]);
  }
  if (blockIdx.x == 0) {
    float s = 0.f;
    for (int b = 0; b < 128; ++b) s += pcs[b * NDIM + tid];
    float q = s * s;
    #pragma unroll
    for (int off = 32; off > 0; off >>= 1) q += __shfl_down(q, off);
    __syncthreads();
    if ((tid & 63) == 0) red[0][tid >> 6] = q;
    __syncthreads();
    if (tid == 0) atomicAdd(&gacc[2], red[0][0] + red[0][1] + red[0][2] + red[0][3]);
  }
  // completion: last block computes the output scalar.
  if (tid == 0) {
    __threadfence();
    int* cnt = (int*)(gacc + 3);
    const int prev = atomicAdd(cnt, 1);
    if (prev == (int)gridDim.x - 1) {
      const float sum8 = atomicAdd(&gacc[0], 0.0f);
      const float S2   = atomicAdd(&gacc[1], 0.0f);
      const float Q    = atomicAdd(&gacc[2], 0.0f);
      const float ref_var = (S2 - Q / (float)NROWS) / ((float)NDIM * (float)(NROWS - 1));
      out[0] = (sum8 / (float)(NROWS * KNN)) / ref_var;
    }
  }
}

extern "C" void kernel_launch(void* const* d_in, const int* in_sizes, int n_in,
                              void* d_out, int out_size, void* d_ws, size_t ws_size,
                              hipStream_t stream) {
  const float* e = (const float*)d_in[0];
  char* ws = (char*)d_ws;
  ushort* ebt = (ushort*)(ws + WS_EBT);
  float* sqn  = (float*)(ws + WS_SQN);
  float* pcs  = (float*)(ws + WS_PCS);
  float* gacc = (float*)(ws + WS_ACC);
  float* knn  = (float*)(ws + WS_KNN);
  float* out  = (float*)d_out;

  const int jsplit = 16;
  const int jrange = NROWS / jsplit;   // 512 -> nT = 16

  hipLaunchKernelGGL(k_prep,  dim3(128), dim3(256), 0, stream, e, ebt, sqn, pcs, gacc);
  hipLaunchKernelGGL(k_main,  dim3(NROWS / BLK_ROWS, jsplit), dim3(256), 0, stream,
                     ebt, sqn, knn, jrange, jsplit);
  hipLaunchKernelGGL(k_final, dim3(NROWS / 256), dim3(256), 0, stream,
                     knn, sqn, pcs, gacc, out, jsplit);
}

// Round 13
// 77.118 us; speedup vs baseline: 1.1603x; 1.1603x over previous
//
#include <hip/hip_runtime.h>
#include <hip/hip_bf16.h>

#define NROWS 8192
#define NDIM  256
#define KNN   8
#define TCOL  32                          // j-cols per LDS tile (16 KiB)
#define BLK_ROWS 128                      // 4 waves x 32 rows (R=1)

typedef __attribute__((ext_vector_type(8)))  short bf16x8;
typedef __attribute__((ext_vector_type(16))) float f32x16;

// ---- workspace layout (bytes) ----
// ebT chunk-major: ushort ebT[32][NROWS][8] — chunk c holds dims 8c..8c+7 of
// every row. Any 32-consecutive-row fragment load = contiguous 512 B.
#define WS_EBT 0                          // 4 MiB
#define WS_SQN (4*1024*1024)              // 32 KiB
#define WS_COL (WS_SQN + 32*1024)         // 1 KiB (colsum, atomics)
#define WS_ACC (WS_COL + 1024)            // 1 KiB (gacc[0..2] + counter)
#define WS_KNN (WS_ACC + 1024)            // [16][NROWS][KNN] f32 = 4 MiB

// e -> bf16 chunk-major, per-row squared norms, colsum via device atomics.
// 256 blocks x 32 rows — full CU coverage (was 128 blocks = 50%).
__global__ void k_prep(const float* __restrict__ e,
                       ushort* __restrict__ ebt,
                       float* __restrict__ sqn,
                       float* __restrict__ colsum) {
  __shared__ float lcs[NDIM];
  const int tid  = threadIdx.x;
  const int lane = tid & 63;
  const int wv   = tid >> 6;
  lcs[tid] = 0.f;
  __syncthreads();
  const int chunk = lane >> 1;
  const int half  = lane & 1;
  float4 cs = {0.f, 0.f, 0.f, 0.f};
  #pragma unroll
  for (int r = 0; r < 8; ++r) {
    const int row = blockIdx.x * 32 + wv * 8 + r;
    const float4 v = *reinterpret_cast<const float4*>(e + (size_t)row * NDIM + lane * 4);
    ushort4 o;
    __hip_bfloat16 b0 = __float2bfloat16(v.x), b1 = __float2bfloat16(v.y);
    __hip_bfloat16 b2 = __float2bfloat16(v.z), b3 = __float2bfloat16(v.w);
    o.x = *reinterpret_cast<ushort*>(&b0); o.y = *reinterpret_cast<ushort*>(&b1);
    o.z = *reinterpret_cast<ushort*>(&b2); o.w = *reinterpret_cast<ushort*>(&b3);
    *reinterpret_cast<ushort4*>(ebt + ((size_t)(chunk * NROWS + row) * 8 + half * 4)) = o;
    float acc = v.x*v.x + v.y*v.y + v.z*v.z + v.w*v.w;
    #pragma unroll
    for (int off = 32; off > 0; off >>= 1) acc += __shfl_down(acc, off);
    if (lane == 0) sqn[row] = acc;
    cs.x += v.x; cs.y += v.y; cs.z += v.z; cs.w += v.w;
  }
  atomicAdd(&lcs[lane * 4 + 0], cs.x);
  atomicAdd(&lcs[lane * 4 + 1], cs.y);
  atomicAdd(&lcs[lane * 4 + 2], cs.z);
  atomicAdd(&lcs[lane * 4 + 3], cs.w);
  __syncthreads();
  atomicAdd(&colsum[tid], lcs[tid]);
}

// ---- selection helpers (MAX-key; key = dot - nj/2, larger = nearer) ----
__device__ __forceinline__ void CEmax(float& x, float& y) {
  const float hi = fmaxf(x, y);
  y = fminf(x, y);
  x = hi;
}
__device__ __forceinline__ void clean8max(float* s) {   // bitonic -> descending
  CEmax(s[0],s[4]); CEmax(s[1],s[5]); CEmax(s[2],s[6]); CEmax(s[3],s[7]);
  CEmax(s[0],s[2]); CEmax(s[1],s[3]); CEmax(s[4],s[6]); CEmax(s[5],s[7]);
  CEmax(s[0],s[1]); CEmax(s[2],s[3]); CEmax(s[4],s[5]); CEmax(s[6],s[7]);
}
__device__ __forceinline__ void ins8max(float* m, const float c) {  // desc insert
  m[7] = __builtin_amdgcn_fmed3f(m[6], m[7], c);
  m[6] = __builtin_amdgcn_fmed3f(m[5], m[6], c);
  m[5] = __builtin_amdgcn_fmed3f(m[4], m[5], c);
  m[4] = __builtin_amdgcn_fmed3f(m[3], m[4], c);
  m[3] = __builtin_amdgcn_fmed3f(m[2], m[3], c);
  m[2] = __builtin_amdgcn_fmed3f(m[1], m[2], c);
  m[1] = __builtin_amdgcn_fmed3f(m[0], m[1], c);
  m[0] = fmaxf(m[0], c);
}
__device__ __forceinline__ void CEmin(float& x, float& y) {
  const float lo = fminf(x, y);
  y = fmaxf(x, y);
  x = lo;
}
__device__ __forceinline__ void clean8min(float* s) {   // bitonic -> ascending
  CEmin(s[0],s[4]); CEmin(s[1],s[5]); CEmin(s[2],s[6]); CEmin(s[3],s[7]);
  CEmin(s[0],s[2]); CEmin(s[1],s[3]); CEmin(s[4],s[6]); CEmin(s[5],s[7]);
  CEmin(s[0],s[1]); CEmin(s[2],s[3]); CEmin(s[4],s[5]); CEmin(s[6],s[7]);
}

// Fused Gram + top-8. r10 structure (R=1, 4 blocks/CU, chunk-major ebT,
// coalesced everywhere, 0-conflict LDS) + T4 counted-vmcnt pipeline:
// tiles t and t+1 always in flight; per iter: wait vmcnt(4) -> s_barrier ->
// BODY(t) -> s_barrier -> STAGE(t+2). The global_load_lds queue is never
// drained inside the loop (vmcnt(0) only on the final iteration) — loads
// overlap compute across barriers (T3/T4, m218: counted vs drain0 = +38-73%).
__launch_bounds__(256, 4)
__global__ void k_main(const ushort* __restrict__ ebt,
                       const float* __restrict__ sqn,
                       float* __restrict__ knn_out,
                       int jrange, int jsplit) {
  __shared__ ushort lbuf[2][TCOL * NDIM];   // 2 x 16 KiB
  char* const lraw = reinterpret_cast<char*>(&lbuf[0][0]);

  const int tid  = threadIdx.x;
  const int lane = tid & 63;
  const int wv   = tid >> 6;
  const int col  = lane & 31;
  const int hi   = lane >> 5;
  const int rowi = blockIdx.x * BLK_ROWS + wv * 32 + col;
  const int split = blockIdx.y;
  const int jbase = split * jrange;

  // i-fragments: chunk 2kk+hi, row rowi -> coalesced 512 B per half-wave.
  bf16x8 ifr[16];
  #pragma unroll
  for (int kk = 0; kk < 16; ++kk)
    ifr[kk] = *reinterpret_cast<const bf16x8*>(
        ebt + (size_t)((2 * kk + hi) * NROWS + rowi) * 8);
  const float ni = sqn[rowi];

  float m[KNN];
  #pragma unroll
  for (int i = 0; i < KNN; ++i) m[i] = -1e30f;

  // hoisted stage source pointers: thread tid covers chunk c = s*8+(tid>>5),
  // col = tid&31; contiguous 512 B per 32 lanes. Advance 32 rows per tile.
  const ushort* sp[4];
  #pragma unroll
  for (int s = 0; s < 4; ++s) {
    const int c = s * 8 + (tid >> 5);
    sp[s] = ebt + (size_t)(c * NROWS + jbase + (tid & 31)) * 8;
  }
  const int lbase = hi * 512 + col * 16;   // ds_read lane base (contiguous)

  auto STAGE = [&](int bufc) {             // 4 loads/thread; advances 1 tile
    #pragma unroll
    for (int s = 0; s < 4; ++s) {
      __builtin_amdgcn_global_load_lds(
          (const __attribute__((address_space(1))) void*)sp[s],
          (__attribute__((address_space(3))) void*)(
              lraw + bufc * 16384 + s * 4096 + wv * 1024),
          16, 0, 0);
      sp[s] += TCOL * 8;
    }
  };

  const float* njp = sqn + jbase;
  const int nT = jrange / TCOL;            // 16

  STAGE(0);                                // tile 0 -> buf 0
  STAGE(1);                                // tile 1 -> buf 1 (8 loads out)

  for (int t = 0; t < nT; ++t) {
    if (t + 1 < nT) {
      asm volatile("s_waitcnt vmcnt(4)" ::: "memory");  // tile t landed
    } else {
      asm volatile("s_waitcnt vmcnt(0)" ::: "memory");  // final: drain
    }
    __builtin_amdgcn_s_barrier();          // all waves' tile-t parts landed
    asm volatile("" ::: "memory");

    // ---- BODY(t), reading buf t&1 ----
    {
      const int bufc = t & 1;
      f32x16 acc;
      #pragma unroll
      for (int g = 0; g < 4; ++g) {
        const float4 nj4 = *reinterpret_cast<const float4*>(njp + g * 8 + hi * 4);
        acc[g*4+0] = -0.5f * nj4.x; acc[g*4+1] = -0.5f * nj4.y;
        acc[g*4+2] = -0.5f * nj4.z; acc[g*4+3] = -0.5f * nj4.w;
      }
      #pragma unroll
      for (int kk = 0; kk < 16; ++kk) {
        const bf16x8 jf = *reinterpret_cast<const bf16x8*>(
            lraw + bufc * 16384 + kk * 1024 + lbase);
        acc = __builtin_amdgcn_mfma_f32_32x32x16_bf16(jf, ifr[kk], acc, 0, 0, 0);
      }
      #pragma unroll
      for (int q = 0; q < 16; ++q) ins8max(m, acc[q]);
      njp += TCOL;
    }

    asm volatile("" ::: "memory");
    __builtin_amdgcn_s_barrier();          // all waves done reading buf t&1
    if (t + 2 < nT) STAGE(t & 1);          // tile t+2 -> buf t&1 (no drain)
  }

  // merge k-half lists (lane <-> lane+32): top-8 of two descending lists is
  // elementwise max(a_k, b_{7-k}) (bitonic) -> clean. dist = ni - 2*key.
  float g[KNN];
  #pragma unroll
  for (int k = 0; k < KNN; ++k)
    g[k] = fmaxf(m[k], __shfl_xor(m[KNN - 1 - k], 32));
  clean8max(g);
  if (hi == 0) {
    float* dst = knn_out + ((size_t)split * NROWS + rowi) * KNN;
    #pragma unroll
    for (int k = 0; k < KNN; ++k)
      dst[k] = fmaxf(fmaf(-2.0f, g[k], ni), 0.0f);   // ascending distances
  }
}

// Merge jsplit ascending sorted 8-lists per row; reduce sum8/S2; block 0
// computes Q from colsum; last finishing block computes the scalar.
__global__ void k_final(const float* __restrict__ knn,
                        const float* __restrict__ sqn,
                        const float* __restrict__ colsum,
                        float* __restrict__ gacc,
                        float* __restrict__ out, int jsplit) {
  const int tid = threadIdx.x;
  const int row = blockIdx.x * blockDim.x + tid;
  float m[KNN];
  const float* p0 = knn + (size_t)row * KNN;
  #pragma unroll
  for (int i = 0; i < KNN; ++i) m[i] = p0[i];
  for (int s = 1; s < jsplit; ++s) {
    const float* p = knn + ((size_t)s * NROWS + row) * KNN;
    float b[KNN];
    #pragma unroll
    for (int i = 0; i < KNN; ++i) b[i] = p[i];
    #pragma unroll
    for (int k = 0; k < KNN; ++k) m[k] = fminf(m[k], b[KNN - 1 - k]);
    clean8min(m);
  }
  float rs = 0.f;
  #pragma unroll
  for (int i = 0; i < KNN; ++i) rs += m[i];
  float s2 = sqn[row];

  __shared__ float red[2][4];
  #pragma unroll
  for (int off = 32; off > 0; off >>= 1) {
    rs += __shfl_down(rs, off);
    s2 += __shfl_down(s2, off);
  }
  if ((tid & 63) == 0) { red[0][tid >> 6] = rs; red[1][tid >> 6] = s2; }
  __syncthreads();
  if (tid == 0) {
    atomicAdd(&gacc[0], red[0][0] + red[0][1] + red[0][2] + red[0][3]);
    atomicAdd(&gacc[1], red[1][0] + red[1][1] + red[1][2] + red[1][3]);
  }
  if (blockIdx.x == 0) {
    const float cs = colsum[tid];
    float q = cs * cs;
    #pragma unroll
    for (int off = 32; off > 0; off >>= 1) q += __shfl_down(q, off);
    __syncthreads();
    if ((tid & 63) == 0) red[0][tid >> 6] = q;
    __syncthreads();
    if (tid == 0) atomicAdd(&gacc[2], red[0][0] + red[0][1] + red[0][2] + red[0][3]);
  }
  // completion: last block computes the output scalar.
  if (tid == 0) {
    __threadfence();
    int* cnt = (int*)(gacc + 3);
    const int prev = atomicAdd(cnt, 1);
    if (prev == (int)gridDim.x - 1) {
      const float sum8 = atomicAdd(&gacc[0], 0.0f);
      const float S2   = atomicAdd(&gacc[1], 0.0f);
      const float Q    = atomicAdd(&gacc[2], 0.0f);
      const float ref_var = (S2 - Q / (float)NROWS) / ((float)NDIM * (float)(NROWS - 1));
      out[0] = (sum8 / (float)(NROWS * KNN)) / ref_var;
    }
  }
}

extern "C" void kernel_launch(void* const* d_in, const int* in_sizes, int n_in,
                              void* d_out, int out_size, void* d_ws, size_t ws_size,
                              hipStream_t stream) {
  const float* e = (const float*)d_in[0];
  char* ws = (char*)d_ws;
  ushort* ebt   = (ushort*)(ws + WS_EBT);
  float* sqn    = (float*)(ws + WS_SQN);
  float* colsum = (float*)(ws + WS_COL);
  float* gacc   = (float*)(ws + WS_ACC);
  float* knn    = (float*)(ws + WS_KNN);
  float* out    = (float*)d_out;

  const int jsplit = 16;
  const int jrange = NROWS / jsplit;   // 512 -> nT = 16

  // zero colsum + gacc + counter (harness doesn't re-poison ws).
  hipMemsetAsync(ws + WS_COL, 0, 2048, stream);

  hipLaunchKernelGGL(k_prep,  dim3(256), dim3(256), 0, stream, e, ebt, sqn, colsum);
  hipLaunchKernelGGL(k_main,  dim3(NROWS / BLK_ROWS, jsplit), dim3(256), 0, stream,
                     ebt, sqn, knn, jrange, jsplit);
  hipLaunchKernelGGL(k_final, dim3(NROWS / 256), dim3(256), 0, stream,
                     knn, sqn, colsum, gacc, out, jsplit);
}